// Round 5
// baseline (445.961 us; speedup 1.0000x reference)
//
#include <hip/hip_runtime.h>

#define NU 50000
#define NE 100000
#define NN 150000          // NU + NE
#define DD 64
#define EUI 1500000

#define TPB 256
#define NBLK 2048          // edge-stride kernels
#define NSB 586            // ceil(NN/256) scan1 blocks
#define NS23 147           // ceil(NN/1024) scan23 blocks
#define NXB 2344           // ceil(NN/64) xw tiles
#define NBF 37500          // NN/4: k_fused blocks (exact)
#define NSC 9375           // NN*DD/4/256: k_scale blocks (exact)

// workspace layout (units: 4-byte words)
#define XWB_OFF    0ull          // 4,800,000 words: xW in bf16 (row = 32 dwords)
#define SSRC_OFF   4800000ull    // 1,500,000 i32: src sorted by dst
#define CNT_OFF    6300000ull    // 150,000 i32
#define ROWPTR_OFF 6450000ull    // 150,001 i32
#define CURSOR_OFF 6600004ull    // 150,000 i32
#define BSUM_OFF   6750004ull    // 586 i32
#define PSUM_OFF   6750590ull    // 37,500 f32
#define SCAL_OFF   6788090ull    // [0] = sum(exp(logits))

// f32 -> bf16 RNE pack of two values into one dword (a = low/even dim)
__device__ __forceinline__ unsigned bfpack(float a, float b) {
  unsigned ua = __float_as_uint(a);
  ua = (ua + 0x7fffu + ((ua >> 16) & 1u)) >> 16;
  unsigned ub = __float_as_uint(b);
  ub = (ub + 0x7fffu + ((ub >> 16) & 1u)) & 0xffff0000u;
  return (ua & 0xffffu) | ub;
}

// ---------------- xW = concat(user_table[uidx], entity_table[iidx]) @ W ------
// LDS-tiled 64x64x64 f32 GEMM per block; epilogue rounds to bf16 (the only
// rounding in the whole pipeline). Row = 64 bf16 = 128 B.
__global__ __launch_bounds__(TPB) void k_xw(const int* __restrict__ uidx,
                                            const int* __restrict__ iidx,
                                            const float* __restrict__ ut,
                                            const float* __restrict__ et,
                                            const float* __restrict__ W,
                                            unsigned* __restrict__ xwb) {
  __shared__ float Ws[DD * DD];   // [k][c]
  __shared__ float Xs[64 * 68];   // [r][k], padded stride 68
  const int t = threadIdx.x;
  {
    const float4* W4 = (const float4*)W;
    float4* Ws4 = (float4*)Ws;
#pragma unroll
    for (int i = 0; i < 4; ++i) Ws4[t + i * TPB] = W4[t + i * TPB];
  }
  {
    const int rl = t >> 2, ch = t & 3;   // 4 threads per row, 4 float4 each
    int row = blockIdx.x * 64 + rl;
    if (row >= NN) row = NN - 1;         // clamp; stores guarded below
    const float4* s4 = (const float4*)((row < NU)
        ? ut + (size_t)uidx[row] * DD
        : et + (size_t)iidx[row - NU] * DD);
    float4* x4 = (float4*)(Xs + rl * 68);
#pragma unroll
    for (int j = 0; j < 4; ++j) x4[ch + 4 * j] = s4[ch + 4 * j];
  }
  __syncthreads();
  const int q = t & 15, g = t >> 4;      // col quad, row group (4 rows)
  float4 acc[4] = {{0,0,0,0},{0,0,0,0},{0,0,0,0},{0,0,0,0}};
#pragma unroll
  for (int kc = 0; kc < 16; ++kc) {
    float4 xb[4], wb[4];
#pragma unroll
    for (int i = 0; i < 4; ++i)
      xb[i] = *(const float4*)(Xs + (4 * g + i) * 68 + 4 * kc);
#pragma unroll
    for (int j = 0; j < 4; ++j)
      wb[j] = *(const float4*)(Ws + (4 * kc + j) * DD + 4 * q);
#pragma unroll
    for (int i = 0; i < 4; ++i) {
      acc[i].x = fmaf(xb[i].x, wb[0].x, acc[i].x);
      acc[i].y = fmaf(xb[i].x, wb[0].y, acc[i].y);
      acc[i].z = fmaf(xb[i].x, wb[0].z, acc[i].z);
      acc[i].w = fmaf(xb[i].x, wb[0].w, acc[i].w);
      acc[i].x = fmaf(xb[i].y, wb[1].x, acc[i].x);
      acc[i].y = fmaf(xb[i].y, wb[1].y, acc[i].y);
      acc[i].z = fmaf(xb[i].y, wb[1].z, acc[i].z);
      acc[i].w = fmaf(xb[i].y, wb[1].w, acc[i].w);
      acc[i].x = fmaf(xb[i].z, wb[2].x, acc[i].x);
      acc[i].y = fmaf(xb[i].z, wb[2].y, acc[i].y);
      acc[i].z = fmaf(xb[i].z, wb[2].z, acc[i].z);
      acc[i].w = fmaf(xb[i].z, wb[2].w, acc[i].w);
      acc[i].x = fmaf(xb[i].w, wb[3].x, acc[i].x);
      acc[i].y = fmaf(xb[i].w, wb[3].y, acc[i].y);
      acc[i].z = fmaf(xb[i].w, wb[3].z, acc[i].z);
      acc[i].w = fmaf(xb[i].w, wb[3].w, acc[i].w);
    }
  }
#pragma unroll
  for (int i = 0; i < 4; ++i) {
    const int row = blockIdx.x * 64 + 4 * g + i;
    if (row < NN) {
      uint2 p;
      p.x = bfpack(acc[i].x, acc[i].y);
      p.y = bfpack(acc[i].z, acc[i].w);
      ((uint2*)(xwb + (size_t)row * 32))[q] = p;
    }
  }
}

// ---------------- histogram of dst ------------------------------------------
__global__ __launch_bounds__(TPB) void k_hist(const int* __restrict__ ei,
                                              int* __restrict__ cnt) {
  for (int e = blockIdx.x * TPB + threadIdx.x; e < EUI; e += gridDim.x * TPB)
    atomicAdd(&cnt[ei[EUI + e]], 1);
}

// ---------------- scan stage 1: per-block exclusive + block sums --------------
__global__ __launch_bounds__(TPB) void k_scan1(int* __restrict__ cnt,
                                               int* __restrict__ bsum) {
  __shared__ int sh[TPB];
  const int t = threadIdx.x;
  const int i = blockIdx.x * TPB + t;
  const int v = (i < NN) ? cnt[i] : 0;
  sh[t] = v;
  __syncthreads();
#pragma unroll
  for (int off = 1; off < TPB; off <<= 1) {
    int add = (t >= off) ? sh[t - off] : 0;
    __syncthreads();
    sh[t] += add;
    __syncthreads();
  }
  if (i < NN) cnt[i] = sh[t] - v;
  if (t == TPB - 1) bsum[blockIdx.x] = sh[t];
}

// ---------------- scan stages 2+3 merged --------------------------------------
// Each block redundantly scans the 586 block sums in LDS (2.3 KB), then
// applies: rowptr[i] = cnt_excl[i] + boff[i/256]; cursor copy for k_fill.
__global__ __launch_bounds__(1024) void k_scan23(const int* __restrict__ excl,
                                                 const int* __restrict__ bsum,
                                                 int* __restrict__ rowptr,
                                                 int* __restrict__ cursor) {
  __shared__ int sh[1024];
  const int t = threadIdx.x;
  const int v = (t < NSB) ? bsum[t] : 0;
  sh[t] = v;
  __syncthreads();
#pragma unroll
  for (int off = 1; off < 1024; off <<= 1) {
    int add = (t >= off) ? sh[t - off] : 0;
    __syncthreads();
    sh[t] += add;
    __syncthreads();
  }
  const int boff = sh[t] - v;  // only meaningful for t<NSB, but we re-read below
  __syncthreads();
  sh[t] = boff;
  __syncthreads();
  const int i = blockIdx.x * 1024 + t;
  if (i < NN) {
    const int r = excl[i] + sh[i >> 8];
    rowptr[i] = r;
    cursor[i] = r;
  }
  if (i == 0) rowptr[NN] = EUI;
}

// ---------------- CSR fill (atomic cursor) ------------------------------------
__global__ __launch_bounds__(TPB) void k_fill(const int* __restrict__ ei,
                                              int* __restrict__ cursor,
                                              int* __restrict__ ssrc) {
  for (int e = blockIdx.x * TPB + threadIdx.x; e < EUI; e += gridDim.x * TPB) {
    const int src = ei[e];
    const int dst = ei[EUI + e];
    const int p = atomicAdd(&cursor[dst], 1);
    ssrc[p] = src;
  }
}

// ---------------- fused logits+exp+aggregate (bf16 gathers) -------------------
// One wave per node; 16 lanes per edge (dwordx2 = 4 bf16 dims/lane), 4 edges
// per iteration. Unnormalized: out[n] = sum_e exp(leaky(dot)) * xW[src];
// psum[block] = partial sum of exp (softmax is shift-invariant and |logit|<~1,
// so no max subtraction needed).
__global__ __launch_bounds__(TPB) void k_fused(const int* __restrict__ rowptr,
                                               const int* __restrict__ ssrc,
                                               const unsigned* __restrict__ xwb,
                                               float* __restrict__ out,
                                               float* __restrict__ psum) {
  const int lane = threadIdx.x & 63;
  const int wv = threadIdx.x >> 6;
  const int sub = lane >> 4;   // edge slot 0..3
  const int q = lane & 15;     // dim quad 0..15
  const int n = blockIdx.x * 4 + wv;  // < NN (NN == 4*NBF)
  const uint2* __restrict__ x2 = (const uint2*)xwb;  // row stride 16 uint2
  const uint2 dv = x2[(size_t)n * 16 + q];
  const float vd0 = __uint_as_float(dv.x << 16);
  const float vd1 = __uint_as_float(dv.x & 0xffff0000u);
  const float vd2 = __uint_as_float(dv.y << 16);
  const float vd3 = __uint_as_float(dv.y & 0xffff0000u);
  const int b = rowptr[n], e = rowptr[n + 1];
  float a0 = 0.f, a1 = 0.f, a2 = 0.f, a3 = 0.f, wacc = 0.f;
  for (int i0 = b; i0 < e; i0 += 4) {
    const int idx = i0 + sub;
    const int safe = (idx < e) ? idx : b;
    const int s = ssrc[safe];
    const uint2 sv = x2[(size_t)s * 16 + q];
    const float v0 = __uint_as_float(sv.x << 16);
    const float v1 = __uint_as_float(sv.x & 0xffff0000u);
    const float v2 = __uint_as_float(sv.y << 16);
    const float v3 = __uint_as_float(sv.y & 0xffff0000u);
    float p = vd0 * v0;
    p = fmaf(vd1, v1, p);
    p = fmaf(vd2, v2, p);
    p = fmaf(vd3, v3, p);
#pragma unroll
    for (int off = 1; off < 16; off <<= 1) p += __shfl_xor(p, off, 64);
    const float lg = (p > 0.f) ? p : 0.2f * p;
    float w = __expf(lg);
    if (idx >= e) w = 0.f;  // kill padded slots
    a0 = fmaf(w, v0, a0);
    a1 = fmaf(w, v1, a1);
    a2 = fmaf(w, v2, a2);
    a3 = fmaf(w, v3, a3);
    if (q == 0) wacc += w;
  }
  // combine the 4 edge slots (lanes with equal q)
#pragma unroll
  for (int off = 16; off < 64; off <<= 1) {
    a0 += __shfl_xor(a0, off, 64);
    a1 += __shfl_xor(a1, off, 64);
    a2 += __shfl_xor(a2, off, 64);
    a3 += __shfl_xor(a3, off, 64);
  }
  if (sub == 0) {
    float4 r = {a0, a1, a2, a3};
    ((float4*)(out + (size_t)n * DD))[q] = r;
  }
  // wacc lives on q==0 lanes (0,16,32,48): two xor steps gather all slots
  wacc += __shfl_xor(wacc, 16, 64);
  wacc += __shfl_xor(wacc, 32, 64);
  __shared__ float sm[4];
  if (lane == 0) sm[wv] = wacc;
  __syncthreads();
  if (threadIdx.x == 0) psum[blockIdx.x] = sm[0] + sm[1] + sm[2] + sm[3];
}

// ---------------- total exp-sum -----------------------------------------------
__global__ __launch_bounds__(TPB) void k_rsum(const float* __restrict__ psum,
                                              float* __restrict__ scal) {
  float s = 0.f;
  for (int i = threadIdx.x; i < NBF; i += TPB) s += psum[i];
#pragma unroll
  for (int off = 32; off; off >>= 1) s += __shfl_xor(s, off, 64);
  __shared__ float sm[4];
  if ((threadIdx.x & 63) == 0) sm[threadIdx.x >> 6] = s;
  __syncthreads();
  if (threadIdx.x == 0) scal[0] = sm[0] + sm[1] + sm[2] + sm[3];
}

// ---------------- out = relu(out / sumexp) ------------------------------------
__global__ __launch_bounds__(TPB) void k_scale(float* __restrict__ out,
                                               const float* __restrict__ scal) {
  const float inv = 1.0f / scal[0];
  const int i = blockIdx.x * TPB + threadIdx.x;
  float4* o4 = (float4*)out;
  float4 v = o4[i];
  v.x = fmaxf(v.x * inv, 0.f);
  v.y = fmaxf(v.y * inv, 0.f);
  v.z = fmaxf(v.z * inv, 0.f);
  v.w = fmaxf(v.w * inv, 0.f);
  o4[i] = v;
}

extern "C" void kernel_launch(void* const* d_in, const int* in_sizes, int n_in,
                              void* d_out, int out_size, void* d_ws, size_t ws_size,
                              hipStream_t stream) {
  const int* uidx = (const int*)d_in[0];
  const int* iidx = (const int*)d_in[1];
  const int* ei_ui = (const int*)d_in[2];
  // d_in[3], d_in[4], d_in[8] (KG graph, W_r): dead code in the reference
  // (x_kg is added into x, then x is fully overwritten by relu(x_ui)).
  const float* ut = (const float*)d_in[5];
  const float* et = (const float*)d_in[6];
  const float* W = (const float*)d_in[7];

  float* out = (float*)d_out;
  float* ws = (float*)d_ws;
  unsigned* xwb = (unsigned*)(ws + XWB_OFF);
  int* ssrc = (int*)(ws + SSRC_OFF);
  int* cnt = (int*)(ws + CNT_OFF);
  int* rowptr = (int*)(ws + ROWPTR_OFF);
  int* cursor = (int*)(ws + CURSOR_OFF);
  int* bsum = (int*)(ws + BSUM_OFF);
  float* psum = ws + PSUM_OFF;
  float* scal = ws + SCAL_OFF;

  hipMemsetAsync(cnt, 0, (size_t)NN * sizeof(int), stream);

  k_xw<<<NXB, TPB, 0, stream>>>(uidx, iidx, ut, et, W, xwb);
  k_hist<<<NBLK, TPB, 0, stream>>>(ei_ui, cnt);
  k_scan1<<<NSB, TPB, 0, stream>>>(cnt, bsum);
  k_scan23<<<NS23, 1024, 0, stream>>>(cnt, bsum, rowptr, cursor);
  k_fill<<<NBLK, TPB, 0, stream>>>(ei_ui, cursor, ssrc);
  k_fused<<<NBF, TPB, 0, stream>>>(rowptr, ssrc, xwb, out, psum);
  k_rsum<<<1, TPB, 0, stream>>>(psum, scal);
  k_scale<<<NSC, TPB, 0, stream>>>(out, scal);
}

// Round 6
// 387.964 us; speedup vs baseline: 1.1495x; 1.1495x over previous
//
#include <hip/hip_runtime.h>

#define NU 50000
#define NE 100000
#define NN 150000          // NU + NE
#define DD 64
#define EUI 1500000

#define TPB 256
#define NBLK 2048          // edge-stride kernels
#define NSB 586            // ceil(NN/256) scan1 blocks
#define NS23 147           // ceil(NN/1024) scan23 blocks
#define NXB 2344           // ceil(NN/64) xw tiles
#define NBF 37500          // NN/4: k_fused blocks (exact)
#define NSC 9375           // NN*DD/4/256: k_scale blocks (exact)

// workspace layout (units: 4-byte words)
#define XWB_OFF    0ull          // 4,800,000 words: xW in bf16 (row = 32 dwords)
#define PD_OFF     4800000ull    // 1,500,000 u32: (rank<<18)|dst per edge
#define SSRC_OFF   6300000ull    // 1,500,000 i32: src sorted by dst
#define CNT_OFF    7800000ull    // 150,000 i32
#define ROWPTR_OFF 7950000ull    // 150,001 i32
#define BSUM_OFF   8100004ull    // 586 i32
#define PSUM_OFF   8100590ull    // 37,500 f32
#define SCAL_OFF   8138090ull    // [0] = sum(exp(logits))

// f32 -> bf16 RNE pack of two values into one dword (a = low/even dim)
__device__ __forceinline__ unsigned bfpack(float a, float b) {
  unsigned ua = __float_as_uint(a);
  ua = (ua + 0x7fffu + ((ua >> 16) & 1u)) >> 16;
  unsigned ub = __float_as_uint(b);
  ub = (ub + 0x7fffu + ((ub >> 16) & 1u)) & 0xffff0000u;
  return (ua & 0xffffu) | ub;
}

// ---------------- xW = concat(user_table[uidx], entity_table[iidx]) @ W ------
// LDS-tiled 64x64x64 f32 GEMM per block; epilogue rounds to bf16 (the only
// rounding in the whole pipeline). Row = 64 bf16 = 128 B.
__global__ __launch_bounds__(TPB) void k_xw(const int* __restrict__ uidx,
                                            const int* __restrict__ iidx,
                                            const float* __restrict__ ut,
                                            const float* __restrict__ et,
                                            const float* __restrict__ W,
                                            unsigned* __restrict__ xwb) {
  __shared__ float Ws[DD * DD];   // [k][c]
  __shared__ float Xs[64 * 68];   // [r][k], padded stride 68
  const int t = threadIdx.x;
  {
    const float4* W4 = (const float4*)W;
    float4* Ws4 = (float4*)Ws;
#pragma unroll
    for (int i = 0; i < 4; ++i) Ws4[t + i * TPB] = W4[t + i * TPB];
  }
  {
    const int rl = t >> 2, ch = t & 3;   // 4 threads per row, 4 float4 each
    int row = blockIdx.x * 64 + rl;
    if (row >= NN) row = NN - 1;         // clamp; stores guarded below
    const float4* s4 = (const float4*)((row < NU)
        ? ut + (size_t)uidx[row] * DD
        : et + (size_t)iidx[row - NU] * DD);
    float4* x4 = (float4*)(Xs + rl * 68);
#pragma unroll
    for (int j = 0; j < 4; ++j) x4[ch + 4 * j] = s4[ch + 4 * j];
  }
  __syncthreads();
  const int q = t & 15, g = t >> 4;      // col quad, row group (4 rows)
  float4 acc[4] = {{0,0,0,0},{0,0,0,0},{0,0,0,0},{0,0,0,0}};
#pragma unroll
  for (int kc = 0; kc < 16; ++kc) {
    float4 xb[4], wb[4];
#pragma unroll
    for (int i = 0; i < 4; ++i)
      xb[i] = *(const float4*)(Xs + (4 * g + i) * 68 + 4 * kc);
#pragma unroll
    for (int j = 0; j < 4; ++j)
      wb[j] = *(const float4*)(Ws + (4 * kc + j) * DD + 4 * q);
#pragma unroll
    for (int i = 0; i < 4; ++i) {
      acc[i].x = fmaf(xb[i].x, wb[0].x, acc[i].x);
      acc[i].y = fmaf(xb[i].x, wb[0].y, acc[i].y);
      acc[i].z = fmaf(xb[i].x, wb[0].z, acc[i].z);
      acc[i].w = fmaf(xb[i].x, wb[0].w, acc[i].w);
      acc[i].x = fmaf(xb[i].y, wb[1].x, acc[i].x);
      acc[i].y = fmaf(xb[i].y, wb[1].y, acc[i].y);
      acc[i].z = fmaf(xb[i].y, wb[1].z, acc[i].z);
      acc[i].w = fmaf(xb[i].y, wb[1].w, acc[i].w);
      acc[i].x = fmaf(xb[i].z, wb[2].x, acc[i].x);
      acc[i].y = fmaf(xb[i].z, wb[2].y, acc[i].y);
      acc[i].z = fmaf(xb[i].z, wb[2].z, acc[i].z);
      acc[i].w = fmaf(xb[i].z, wb[2].w, acc[i].w);
      acc[i].x = fmaf(xb[i].w, wb[3].x, acc[i].x);
      acc[i].y = fmaf(xb[i].w, wb[3].y, acc[i].y);
      acc[i].z = fmaf(xb[i].w, wb[3].z, acc[i].z);
      acc[i].w = fmaf(xb[i].w, wb[3].w, acc[i].w);
    }
  }
#pragma unroll
  for (int i = 0; i < 4; ++i) {
    const int row = blockIdx.x * 64 + 4 * g + i;
    if (row < NN) {
      uint2 p;
      p.x = bfpack(acc[i].x, acc[i].y);
      p.y = bfpack(acc[i].z, acc[i].w);
      ((uint2*)(xwb + (size_t)row * 32))[q] = p;
    }
  }
}

// ---------------- histogram of dst + packed (rank<<18)|dst --------------------
// rank = position within the dst bucket (max degree ~35 << 2^14, dst < 2^18).
__global__ __launch_bounds__(TPB) void k_hist(const int* __restrict__ ei,
                                              int* __restrict__ cnt,
                                              unsigned* __restrict__ pd) {
  for (int e = blockIdx.x * TPB + threadIdx.x; e < EUI; e += gridDim.x * TPB) {
    const int dst = ei[EUI + e];
    const unsigned r = (unsigned)atomicAdd(&cnt[dst], 1);
    pd[e] = (r << 18) | (unsigned)dst;
  }
}

// ---------------- scan stage 1: per-block exclusive + block sums --------------
__global__ __launch_bounds__(TPB) void k_scan1(int* __restrict__ cnt,
                                               int* __restrict__ bsum) {
  __shared__ int sh[TPB];
  const int t = threadIdx.x;
  const int i = blockIdx.x * TPB + t;
  const int v = (i < NN) ? cnt[i] : 0;
  sh[t] = v;
  __syncthreads();
#pragma unroll
  for (int off = 1; off < TPB; off <<= 1) {
    int add = (t >= off) ? sh[t - off] : 0;
    __syncthreads();
    sh[t] += add;
    __syncthreads();
  }
  if (i < NN) cnt[i] = sh[t] - v;
  if (t == TPB - 1) bsum[blockIdx.x] = sh[t];
}

// ---------------- scan stages 2+3 merged --------------------------------------
// Each block redundantly scans the 586 block sums in LDS, then applies:
// rowptr[i] = cnt_excl[i] + boff[i/256].
__global__ __launch_bounds__(1024) void k_scan23(const int* __restrict__ excl,
                                                 const int* __restrict__ bsum,
                                                 int* __restrict__ rowptr) {
  __shared__ int sh[1024];
  const int t = threadIdx.x;
  const int v = (t < NSB) ? bsum[t] : 0;
  sh[t] = v;
  __syncthreads();
#pragma unroll
  for (int off = 1; off < 1024; off <<= 1) {
    int add = (t >= off) ? sh[t - off] : 0;
    __syncthreads();
    sh[t] += add;
    __syncthreads();
  }
  const int boff = sh[t] - v;
  __syncthreads();
  sh[t] = boff;
  __syncthreads();
  const int i = blockIdx.x * 1024 + t;
  if (i < NN) rowptr[i] = excl[i] + sh[i >> 8];
  if (i == 0) rowptr[NN] = EUI;
}

// ---------------- CSR fill (no atomics: p = rowptr[dst] + rank) ---------------
__global__ __launch_bounds__(TPB) void k_fill(const int* __restrict__ ei,
                                              const unsigned* __restrict__ pd,
                                              const int* __restrict__ rowptr,
                                              int* __restrict__ ssrc) {
  for (int e = blockIdx.x * TPB + threadIdx.x; e < EUI; e += gridDim.x * TPB) {
    const unsigned p = pd[e];
    ssrc[rowptr[p & 0x3ffffu] + (int)(p >> 18)] = ei[e];
  }
}

// ---------------- fused logits+exp+aggregate (bf16 gathers) -------------------
// One wave per node; 16 lanes per edge (dwordx2 = 4 bf16 dims/lane), 4 edges
// per iteration. Unnormalized: out[n] = sum_e exp(leaky(dot)) * xW[src];
// psum[block] = partial sum of exp (softmax is shift-invariant and |logit|<~1,
// so no max subtraction needed).
__global__ __launch_bounds__(TPB) void k_fused(const int* __restrict__ rowptr,
                                               const int* __restrict__ ssrc,
                                               const unsigned* __restrict__ xwb,
                                               float* __restrict__ out,
                                               float* __restrict__ psum) {
  const int lane = threadIdx.x & 63;
  const int wv = threadIdx.x >> 6;
  const int sub = lane >> 4;   // edge slot 0..3
  const int q = lane & 15;     // dim quad 0..15
  const int n = blockIdx.x * 4 + wv;  // < NN (NN == 4*NBF)
  const uint2* __restrict__ x2 = (const uint2*)xwb;  // row stride 16 uint2
  const uint2 dv = x2[(size_t)n * 16 + q];
  const float vd0 = __uint_as_float(dv.x << 16);
  const float vd1 = __uint_as_float(dv.x & 0xffff0000u);
  const float vd2 = __uint_as_float(dv.y << 16);
  const float vd3 = __uint_as_float(dv.y & 0xffff0000u);
  const int b = rowptr[n], e = rowptr[n + 1];
  float a0 = 0.f, a1 = 0.f, a2 = 0.f, a3 = 0.f, wacc = 0.f;
  for (int i0 = b; i0 < e; i0 += 4) {
    const int idx = i0 + sub;
    const int safe = (idx < e) ? idx : b;
    const int s = ssrc[safe];
    const uint2 sv = x2[(size_t)s * 16 + q];
    const float v0 = __uint_as_float(sv.x << 16);
    const float v1 = __uint_as_float(sv.x & 0xffff0000u);
    const float v2 = __uint_as_float(sv.y << 16);
    const float v3 = __uint_as_float(sv.y & 0xffff0000u);
    float p = vd0 * v0;
    p = fmaf(vd1, v1, p);
    p = fmaf(vd2, v2, p);
    p = fmaf(vd3, v3, p);
#pragma unroll
    for (int off = 1; off < 16; off <<= 1) p += __shfl_xor(p, off, 64);
    const float lg = (p > 0.f) ? p : 0.2f * p;
    float w = __expf(lg);
    if (idx >= e) w = 0.f;  // kill padded slots
    a0 = fmaf(w, v0, a0);
    a1 = fmaf(w, v1, a1);
    a2 = fmaf(w, v2, a2);
    a3 = fmaf(w, v3, a3);
    if (q == 0) wacc += w;
  }
  // combine the 4 edge slots (lanes with equal q)
#pragma unroll
  for (int off = 16; off < 64; off <<= 1) {
    a0 += __shfl_xor(a0, off, 64);
    a1 += __shfl_xor(a1, off, 64);
    a2 += __shfl_xor(a2, off, 64);
    a3 += __shfl_xor(a3, off, 64);
  }
  if (sub == 0) {
    float4 r = {a0, a1, a2, a3};
    ((float4*)(out + (size_t)n * DD))[q] = r;
  }
  // wacc lives on q==0 lanes (0,16,32,48): two xor steps gather all slots
  wacc += __shfl_xor(wacc, 16, 64);
  wacc += __shfl_xor(wacc, 32, 64);
  __shared__ float sm[4];
  if (lane == 0) sm[wv] = wacc;
  __syncthreads();
  if (threadIdx.x == 0) psum[blockIdx.x] = sm[0] + sm[1] + sm[2] + sm[3];
}

// ---------------- total exp-sum -----------------------------------------------
__global__ __launch_bounds__(TPB) void k_rsum(const float* __restrict__ psum,
                                              float* __restrict__ scal) {
  float s = 0.f;
  for (int i = threadIdx.x; i < NBF; i += TPB) s += psum[i];
#pragma unroll
  for (int off = 32; off; off >>= 1) s += __shfl_xor(s, off, 64);
  __shared__ float sm[4];
  if ((threadIdx.x & 63) == 0) sm[threadIdx.x >> 6] = s;
  __syncthreads();
  if (threadIdx.x == 0) scal[0] = sm[0] + sm[1] + sm[2] + sm[3];
}

// ---------------- out = relu(out / sumexp) ------------------------------------
__global__ __launch_bounds__(TPB) void k_scale(float* __restrict__ out,
                                               const float* __restrict__ scal) {
  const float inv = 1.0f / scal[0];
  const int i = blockIdx.x * TPB + threadIdx.x;
  float4* o4 = (float4*)out;
  float4 v = o4[i];
  v.x = fmaxf(v.x * inv, 0.f);
  v.y = fmaxf(v.y * inv, 0.f);
  v.z = fmaxf(v.z * inv, 0.f);
  v.w = fmaxf(v.w * inv, 0.f);
  o4[i] = v;
}

extern "C" void kernel_launch(void* const* d_in, const int* in_sizes, int n_in,
                              void* d_out, int out_size, void* d_ws, size_t ws_size,
                              hipStream_t stream) {
  const int* uidx = (const int*)d_in[0];
  const int* iidx = (const int*)d_in[1];
  const int* ei_ui = (const int*)d_in[2];
  // d_in[3], d_in[4], d_in[8] (KG graph, W_r): dead code in the reference
  // (x_kg is added into x, then x is fully overwritten by relu(x_ui)).
  const float* ut = (const float*)d_in[5];
  const float* et = (const float*)d_in[6];
  const float* W = (const float*)d_in[7];

  float* out = (float*)d_out;
  float* ws = (float*)d_ws;
  unsigned* xwb = (unsigned*)(ws + XWB_OFF);
  unsigned* pd = (unsigned*)(ws + PD_OFF);
  int* ssrc = (int*)(ws + SSRC_OFF);
  int* cnt = (int*)(ws + CNT_OFF);
  int* rowptr = (int*)(ws + ROWPTR_OFF);
  int* bsum = (int*)(ws + BSUM_OFF);
  float* psum = ws + PSUM_OFF;
  float* scal = ws + SCAL_OFF;

  hipMemsetAsync(cnt, 0, (size_t)NN * sizeof(int), stream);

  k_xw<<<NXB, TPB, 0, stream>>>(uidx, iidx, ut, et, W, xwb);
  k_hist<<<NBLK, TPB, 0, stream>>>(ei_ui, cnt, pd);
  k_scan1<<<NSB, TPB, 0, stream>>>(cnt, bsum);
  k_scan23<<<NS23, 1024, 0, stream>>>(cnt, bsum, rowptr);
  k_fill<<<NBLK, TPB, 0, stream>>>(ei_ui, pd, rowptr, ssrc);
  k_fused<<<NBF, TPB, 0, stream>>>(rowptr, ssrc, xwb, out, psum);
  k_rsum<<<1, TPB, 0, stream>>>(psum, scal);
  k_scale<<<NSC, TPB, 0, stream>>>(out, scal);
}

// Round 7
// 357.804 us; speedup vs baseline: 1.2464x; 1.0843x over previous
//
#include <hip/hip_runtime.h>

#define NU 50000
#define NE 100000
#define NN 150000          // NU + NE
#define DD 64
#define EUI 1500000

#define TPB 256
#define NBLK 2048          // edge-stride kernels
#define NSB 586            // ceil(NN/256) scan1 blocks
#define NS23 147           // ceil(NN/1024) scan23 blocks
#define NXB 2344           // ceil(NN/64) xw tiles
#define NBF 37500          // NN/4: k_fused blocks (exact)
#define NSC 9375           // NN*DD/4/256: k_scale blocks (exact)

// workspace layout (units: 4-byte words)
#define XWB_OFF    0ull          // 4,800,000 words: xW in bf16 (row = 32 dwords)
#define PD_OFF     4800000ull    // 1,500,000 u32: (rank<<18)|dst per edge
#define SSRC_OFF   6300000ull    // 1,500,000 i32: src sorted by dst
#define CNT_OFF    7800000ull    // 150,000 i32
#define ROWPTR_OFF 7950000ull    // 150,001 i32
#define BSUM_OFF   8100004ull    // 586 i32
#define PSUM_OFF   8100590ull    // 37,500 f32
#define SCAL_OFF   8138090ull    // [0] = sum(exp(logits))

// f32 -> bf16 RNE pack of two values into one dword (a = low/even dim)
__device__ __forceinline__ unsigned bfpack(float a, float b) {
  unsigned ua = __float_as_uint(a);
  ua = (ua + 0x7fffu + ((ua >> 16) & 1u)) >> 16;
  unsigned ub = __float_as_uint(b);
  ub = (ub + 0x7fffu + ((ub >> 16) & 1u)) & 0xffff0000u;
  return (ua & 0xffffu) | ub;
}

// ---------------- xW = concat(user_table[uidx], entity_table[iidx]) @ W ------
// LDS-tiled 64x64x64 f32 GEMM; kc loop deliberately NOT unrolled: round-6
// full unroll let the scheduler hoist all 64 ds_read_b128 -> VGPR 232,
// occupancy 10%, 88 us. With unroll(1) live set = acc16+wb16+xb4 ~= 56 VGPR.
__global__ __launch_bounds__(TPB) void k_xw(const int* __restrict__ uidx,
                                            const int* __restrict__ iidx,
                                            const float* __restrict__ ut,
                                            const float* __restrict__ et,
                                            const float* __restrict__ W,
                                            unsigned* __restrict__ xwb) {
  __shared__ float Ws[DD * DD];   // [k][c]
  __shared__ float Xs[64 * 68];   // [r][k], padded stride 68
  const int t = threadIdx.x;
  {
    const float4* W4 = (const float4*)W;
    float4* Ws4 = (float4*)Ws;
#pragma unroll
    for (int i = 0; i < 4; ++i) Ws4[t + i * TPB] = W4[t + i * TPB];
  }
  {
    const int rl = t >> 2, ch = t & 3;   // 4 threads per row, 4 float4 each
    int row = blockIdx.x * 64 + rl;
    if (row >= NN) row = NN - 1;         // clamp; stores guarded below
    const float4* s4 = (const float4*)((row < NU)
        ? ut + (size_t)uidx[row] * DD
        : et + (size_t)iidx[row - NU] * DD);
    float4* x4 = (float4*)(Xs + rl * 68);
#pragma unroll
    for (int j = 0; j < 4; ++j) x4[ch + 4 * j] = s4[ch + 4 * j];
  }
  __syncthreads();
  const int q = t & 15, g = t >> 4;      // col quad, row group (4 rows)
  float4 acc[4] = {{0,0,0,0},{0,0,0,0},{0,0,0,0},{0,0,0,0}};
  const float* __restrict__ wsq = Ws + 4 * q;
  const float* __restrict__ xsg = Xs + (4 * g) * 68;
#pragma unroll 1
  for (int kc = 0; kc < 16; ++kc) {
    const float4 w0 = *(const float4*)(wsq + (4 * kc + 0) * DD);
    const float4 w1 = *(const float4*)(wsq + (4 * kc + 1) * DD);
    const float4 w2 = *(const float4*)(wsq + (4 * kc + 2) * DD);
    const float4 w3 = *(const float4*)(wsq + (4 * kc + 3) * DD);
#pragma unroll
    for (int i = 0; i < 4; ++i) {
      const float4 x = *(const float4*)(xsg + i * 68 + 4 * kc);
      acc[i].x = fmaf(x.x, w0.x, acc[i].x);
      acc[i].y = fmaf(x.x, w0.y, acc[i].y);
      acc[i].z = fmaf(x.x, w0.z, acc[i].z);
      acc[i].w = fmaf(x.x, w0.w, acc[i].w);
      acc[i].x = fmaf(x.y, w1.x, acc[i].x);
      acc[i].y = fmaf(x.y, w1.y, acc[i].y);
      acc[i].z = fmaf(x.y, w1.z, acc[i].z);
      acc[i].w = fmaf(x.y, w1.w, acc[i].w);
      acc[i].x = fmaf(x.z, w2.x, acc[i].x);
      acc[i].y = fmaf(x.z, w2.y, acc[i].y);
      acc[i].z = fmaf(x.z, w2.z, acc[i].z);
      acc[i].w = fmaf(x.z, w2.w, acc[i].w);
      acc[i].x = fmaf(x.w, w3.x, acc[i].x);
      acc[i].y = fmaf(x.w, w3.y, acc[i].y);
      acc[i].z = fmaf(x.w, w3.z, acc[i].z);
      acc[i].w = fmaf(x.w, w3.w, acc[i].w);
    }
  }
#pragma unroll
  for (int i = 0; i < 4; ++i) {
    const int row = blockIdx.x * 64 + 4 * g + i;
    if (row < NN) {
      uint2 p;
      p.x = bfpack(acc[i].x, acc[i].y);
      p.y = bfpack(acc[i].z, acc[i].w);
      ((uint2*)(xwb + (size_t)row * 32))[q] = p;
    }
  }
}

// ---------------- histogram of dst + packed (rank<<18)|dst --------------------
// rank = position within the dst bucket (max degree ~35 << 2^14, dst < 2^18).
__global__ __launch_bounds__(TPB) void k_hist(const int* __restrict__ ei,
                                              int* __restrict__ cnt,
                                              unsigned* __restrict__ pd) {
  for (int e = blockIdx.x * TPB + threadIdx.x; e < EUI; e += gridDim.x * TPB) {
    const int dst = ei[EUI + e];
    const unsigned r = (unsigned)atomicAdd(&cnt[dst], 1);
    pd[e] = (r << 18) | (unsigned)dst;
  }
}

// ---------------- scan stage 1: per-block exclusive + block sums --------------
__global__ __launch_bounds__(TPB) void k_scan1(int* __restrict__ cnt,
                                               int* __restrict__ bsum) {
  __shared__ int sh[TPB];
  const int t = threadIdx.x;
  const int i = blockIdx.x * TPB + t;
  const int v = (i < NN) ? cnt[i] : 0;
  sh[t] = v;
  __syncthreads();
#pragma unroll
  for (int off = 1; off < TPB; off <<= 1) {
    int add = (t >= off) ? sh[t - off] : 0;
    __syncthreads();
    sh[t] += add;
    __syncthreads();
  }
  if (i < NN) cnt[i] = sh[t] - v;
  if (t == TPB - 1) bsum[blockIdx.x] = sh[t];
}

// ---------------- scan stages 2+3 merged --------------------------------------
__global__ __launch_bounds__(1024) void k_scan23(const int* __restrict__ excl,
                                                 const int* __restrict__ bsum,
                                                 int* __restrict__ rowptr) {
  __shared__ int sh[1024];
  const int t = threadIdx.x;
  const int v = (t < NSB) ? bsum[t] : 0;
  sh[t] = v;
  __syncthreads();
#pragma unroll
  for (int off = 1; off < 1024; off <<= 1) {
    int add = (t >= off) ? sh[t - off] : 0;
    __syncthreads();
    sh[t] += add;
    __syncthreads();
  }
  const int boff = sh[t] - v;
  __syncthreads();
  sh[t] = boff;
  __syncthreads();
  const int i = blockIdx.x * 1024 + t;
  if (i < NN) rowptr[i] = excl[i] + sh[i >> 8];
  if (i == 0) rowptr[NN] = EUI;
}

// ---------------- CSR fill (no atomics: p = rowptr[dst] + rank) ---------------
__global__ __launch_bounds__(TPB) void k_fill(const int* __restrict__ ei,
                                              const unsigned* __restrict__ pd,
                                              const int* __restrict__ rowptr,
                                              int* __restrict__ ssrc) {
  for (int e = blockIdx.x * TPB + threadIdx.x; e < EUI; e += gridDim.x * TPB) {
    const unsigned p = pd[e];
    ssrc[rowptr[p & 0x3ffffu] + (int)(p >> 18)] = ei[e];
  }
}

// ---------------- fused logits+exp+aggregate (bf16 gathers) -------------------
// One wave per node; 16 lanes per edge (dwordx2 = 4 bf16 dims/lane), 4 edges
// per iteration. Unnormalized: out[n] = sum_e exp(leaky(dot)) * xW[src];
// psum[block] = partial sum of exp (softmax is shift-invariant and |logit|<~1,
// so no max subtraction needed).
__global__ __launch_bounds__(TPB) void k_fused(const int* __restrict__ rowptr,
                                               const int* __restrict__ ssrc,
                                               const unsigned* __restrict__ xwb,
                                               float* __restrict__ out,
                                               float* __restrict__ psum) {
  const int lane = threadIdx.x & 63;
  const int wv = threadIdx.x >> 6;
  const int sub = lane >> 4;   // edge slot 0..3
  const int q = lane & 15;     // dim quad 0..15
  const int n = blockIdx.x * 4 + wv;  // < NN (NN == 4*NBF)
  const uint2* __restrict__ x2 = (const uint2*)xwb;  // row stride 16 uint2
  const uint2 dv = x2[(size_t)n * 16 + q];
  const float vd0 = __uint_as_float(dv.x << 16);
  const float vd1 = __uint_as_float(dv.x & 0xffff0000u);
  const float vd2 = __uint_as_float(dv.y << 16);
  const float vd3 = __uint_as_float(dv.y & 0xffff0000u);
  const int b = rowptr[n], e = rowptr[n + 1];
  float a0 = 0.f, a1 = 0.f, a2 = 0.f, a3 = 0.f, wacc = 0.f;
  for (int i0 = b; i0 < e; i0 += 4) {
    const int idx = i0 + sub;
    const int safe = (idx < e) ? idx : b;
    const int s = ssrc[safe];
    const uint2 sv = x2[(size_t)s * 16 + q];
    const float v0 = __uint_as_float(sv.x << 16);
    const float v1 = __uint_as_float(sv.x & 0xffff0000u);
    const float v2 = __uint_as_float(sv.y << 16);
    const float v3 = __uint_as_float(sv.y & 0xffff0000u);
    float p = vd0 * v0;
    p = fmaf(vd1, v1, p);
    p = fmaf(vd2, v2, p);
    p = fmaf(vd3, v3, p);
#pragma unroll
    for (int off = 1; off < 16; off <<= 1) p += __shfl_xor(p, off, 64);
    const float lg = (p > 0.f) ? p : 0.2f * p;
    float w = __expf(lg);
    if (idx >= e) w = 0.f;  // kill padded slots
    a0 = fmaf(w, v0, a0);
    a1 = fmaf(w, v1, a1);
    a2 = fmaf(w, v2, a2);
    a3 = fmaf(w, v3, a3);
    if (q == 0) wacc += w;
  }
  // combine the 4 edge slots (lanes with equal q)
#pragma unroll
  for (int off = 16; off < 64; off <<= 1) {
    a0 += __shfl_xor(a0, off, 64);
    a1 += __shfl_xor(a1, off, 64);
    a2 += __shfl_xor(a2, off, 64);
    a3 += __shfl_xor(a3, off, 64);
  }
  if (sub == 0) {
    float4 r = {a0, a1, a2, a3};
    ((float4*)(out + (size_t)n * DD))[q] = r;
  }
  // wacc lives on q==0 lanes (0,16,32,48): two xor steps gather all slots
  wacc += __shfl_xor(wacc, 16, 64);
  wacc += __shfl_xor(wacc, 32, 64);
  __shared__ float sm[4];
  if (lane == 0) sm[wv] = wacc;
  __syncthreads();
  if (threadIdx.x == 0) psum[blockIdx.x] = sm[0] + sm[1] + sm[2] + sm[3];
}

// ---------------- total exp-sum -----------------------------------------------
__global__ __launch_bounds__(TPB) void k_rsum(const float* __restrict__ psum,
                                              float* __restrict__ scal) {
  float s = 0.f;
  for (int i = threadIdx.x; i < NBF; i += TPB) s += psum[i];
#pragma unroll
  for (int off = 32; off; off >>= 1) s += __shfl_xor(s, off, 64);
  __shared__ float sm[4];
  if ((threadIdx.x & 63) == 0) sm[threadIdx.x >> 6] = s;
  __syncthreads();
  if (threadIdx.x == 0) scal[0] = sm[0] + sm[1] + sm[2] + sm[3];
}

// ---------------- out = relu(out / sumexp) ------------------------------------
__global__ __launch_bounds__(TPB) void k_scale(float* __restrict__ out,
                                               const float* __restrict__ scal) {
  const float inv = 1.0f / scal[0];
  const int i = blockIdx.x * TPB + threadIdx.x;
  float4* o4 = (float4*)out;
  float4 v = o4[i];
  v.x = fmaxf(v.x * inv, 0.f);
  v.y = fmaxf(v.y * inv, 0.f);
  v.z = fmaxf(v.z * inv, 0.f);
  v.w = fmaxf(v.w * inv, 0.f);
  o4[i] = v;
}

extern "C" void kernel_launch(void* const* d_in, const int* in_sizes, int n_in,
                              void* d_out, int out_size, void* d_ws, size_t ws_size,
                              hipStream_t stream) {
  const int* uidx = (const int*)d_in[0];
  const int* iidx = (const int*)d_in[1];
  const int* ei_ui = (const int*)d_in[2];
  // d_in[3], d_in[4], d_in[8] (KG graph, W_r): dead code in the reference
  // (x_kg is added into x, then x is fully overwritten by relu(x_ui)).
  const float* ut = (const float*)d_in[5];
  const float* et = (const float*)d_in[6];
  const float* W = (const float*)d_in[7];

  float* out = (float*)d_out;
  float* ws = (float*)d_ws;
  unsigned* xwb = (unsigned*)(ws + XWB_OFF);
  unsigned* pd = (unsigned*)(ws + PD_OFF);
  int* ssrc = (int*)(ws + SSRC_OFF);
  int* cnt = (int*)(ws + CNT_OFF);
  int* rowptr = (int*)(ws + ROWPTR_OFF);
  int* bsum = (int*)(ws + BSUM_OFF);
  float* psum = ws + PSUM_OFF;
  float* scal = ws + SCAL_OFF;

  hipMemsetAsync(cnt, 0, (size_t)NN * sizeof(int), stream);

  k_xw<<<NXB, TPB, 0, stream>>>(uidx, iidx, ut, et, W, xwb);
  k_hist<<<NBLK, TPB, 0, stream>>>(ei_ui, cnt, pd);
  k_scan1<<<NSB, TPB, 0, stream>>>(cnt, bsum);
  k_scan23<<<NS23, 1024, 0, stream>>>(cnt, bsum, rowptr);
  k_fill<<<NBLK, TPB, 0, stream>>>(ei_ui, pd, rowptr, ssrc);
  k_fused<<<NBF, TPB, 0, stream>>>(rowptr, ssrc, xwb, out, psum);
  k_rsum<<<1, TPB, 0, stream>>>(psum, scal);
  k_scale<<<NSC, TPB, 0, stream>>>(out, scal);
}

// Round 9
// 283.264 us; speedup vs baseline: 1.5744x; 1.2631x over previous
//
#include <hip/hip_runtime.h>

#define NU 50000
#define NE 100000
#define NN 150000          // NU + NE
#define DD 64
#define EUI 1500000

#define TPB 256
#define NBLK 2048          // edge-stride kernels
#define NSB 586            // ceil(NN/256) scan1 blocks
#define NS23 147           // ceil(NN/1024) scan23 blocks
#define NXB 2344           // ceil(NN/64) xw tiles
#define NBF2 9375          // NN/16: k_fused blocks (4 waves x 4 nodes each)
#define NSC 9375           // NN*DD/4/256: k_scale blocks (exact)

// workspace layout (units: 4-byte words)
#define XWB_OFF    0ull          // 4,800,000 words: xW in bf16 (row = 32 dwords)
#define PD_OFF     4800000ull    // 1,500,000 u32: (rank<<18)|dst per edge
#define SSRC_OFF   6300000ull    // 1,500,000 i32: src sorted by dst
#define CNT_OFF    7800000ull    // 150,000 i32
#define ROWPTR_OFF 7950000ull    // 150,001 i32
#define BSUM_OFF   8100004ull    // 586 i32
#define PSUM_OFF   8100590ull    // 9,375 f32
#define SCAL_OFF   8110000ull    // [0] = sum(exp(logits))

// f32 -> bf16 RNE pack of two values into one dword (a = low/even dim)
__device__ __forceinline__ unsigned bfpack(float a, float b) {
  unsigned ua = __float_as_uint(a);
  ua = (ua + 0x7fffu + ((ua >> 16) & 1u)) >> 16;
  unsigned ub = __float_as_uint(b);
  ub = (ub + 0x7fffu + ((ub >> 16) & 1u)) & 0xffff0000u;
  return (ua & 0xffffu) | ub;
}

// x + dpp_perm(x) on the VALU pipe (no LDS/ds ops). ctrl must be an
// immediate -> template parameter (round-8 compile failure: function arg
// isn't a constant at frontend check time).
template <int CTRL>
__device__ __forceinline__ float dpp_add(float x) {
  int y = __builtin_amdgcn_update_dpp(0, __float_as_int(x), CTRL, 0xF, 0xF, false);
  return x + __int_as_float(y);
}
// full sum across a 16-lane DPP row: +ror4, +ror8 (stride-4 class sums),
// then quad_perm xor1, xor2 (complete within-quad).
__device__ __forceinline__ float row16_sum(float x) {
  x = dpp_add<0x124>(x);  // row_ror:4
  x = dpp_add<0x128>(x);  // row_ror:8
  x = dpp_add<0xB1>(x);   // quad_perm [1,0,3,2]  (xor 1)
  x = dpp_add<0x4E>(x);   // quad_perm [2,3,0,1]  (xor 2)
  return x;
}

// ---------------- xW = concat(user_table[uidx], entity_table[iidx]) @ W ------
// LDS-tiled 64x64x64 f32 GEMM; kc loop deliberately NOT unrolled (full unroll
// hoisted all 64 ds_read_b128 -> VGPR 232, occupancy 10%, 88 us in round 6).
__global__ __launch_bounds__(TPB) void k_xw(const int* __restrict__ uidx,
                                            const int* __restrict__ iidx,
                                            const float* __restrict__ ut,
                                            const float* __restrict__ et,
                                            const float* __restrict__ W,
                                            unsigned* __restrict__ xwb) {
  __shared__ float Ws[DD * DD];   // [k][c]
  __shared__ float Xs[64 * 68];   // [r][k], padded stride 68
  const int t = threadIdx.x;
  {
    const float4* W4 = (const float4*)W;
    float4* Ws4 = (float4*)Ws;
#pragma unroll
    for (int i = 0; i < 4; ++i) Ws4[t + i * TPB] = W4[t + i * TPB];
  }
  {
    const int rl = t >> 2, ch = t & 3;   // 4 threads per row, 4 float4 each
    int row = blockIdx.x * 64 + rl;
    if (row >= NN) row = NN - 1;         // clamp; stores guarded below
    const float4* s4 = (const float4*)((row < NU)
        ? ut + (size_t)uidx[row] * DD
        : et + (size_t)iidx[row - NU] * DD);
    float4* x4 = (float4*)(Xs + rl * 68);
#pragma unroll
    for (int j = 0; j < 4; ++j) x4[ch + 4 * j] = s4[ch + 4 * j];
  }
  __syncthreads();
  const int q = t & 15, g = t >> 4;      // col quad, row group (4 rows)
  float4 acc[4] = {{0,0,0,0},{0,0,0,0},{0,0,0,0},{0,0,0,0}};
  const float* __restrict__ wsq = Ws + 4 * q;
  const float* __restrict__ xsg = Xs + (4 * g) * 68;
#pragma unroll 1
  for (int kc = 0; kc < 16; ++kc) {
    const float4 w0 = *(const float4*)(wsq + (4 * kc + 0) * DD);
    const float4 w1 = *(const float4*)(wsq + (4 * kc + 1) * DD);
    const float4 w2 = *(const float4*)(wsq + (4 * kc + 2) * DD);
    const float4 w3 = *(const float4*)(wsq + (4 * kc + 3) * DD);
#pragma unroll
    for (int i = 0; i < 4; ++i) {
      const float4 x = *(const float4*)(xsg + i * 68 + 4 * kc);
      acc[i].x = fmaf(x.x, w0.x, acc[i].x);
      acc[i].y = fmaf(x.x, w0.y, acc[i].y);
      acc[i].z = fmaf(x.x, w0.z, acc[i].z);
      acc[i].w = fmaf(x.x, w0.w, acc[i].w);
      acc[i].x = fmaf(x.y, w1.x, acc[i].x);
      acc[i].y = fmaf(x.y, w1.y, acc[i].y);
      acc[i].z = fmaf(x.y, w1.z, acc[i].z);
      acc[i].w = fmaf(x.y, w1.w, acc[i].w);
      acc[i].x = fmaf(x.z, w2.x, acc[i].x);
      acc[i].y = fmaf(x.z, w2.y, acc[i].y);
      acc[i].z = fmaf(x.z, w2.z, acc[i].z);
      acc[i].w = fmaf(x.z, w2.w, acc[i].w);
      acc[i].x = fmaf(x.w, w3.x, acc[i].x);
      acc[i].y = fmaf(x.w, w3.y, acc[i].y);
      acc[i].z = fmaf(x.w, w3.z, acc[i].z);
      acc[i].w = fmaf(x.w, w3.w, acc[i].w);
    }
  }
#pragma unroll
  for (int i = 0; i < 4; ++i) {
    const int row = blockIdx.x * 64 + 4 * g + i;
    if (row < NN) {
      uint2 p;
      p.x = bfpack(acc[i].x, acc[i].y);
      p.y = bfpack(acc[i].z, acc[i].w);
      ((uint2*)(xwb + (size_t)row * 32))[q] = p;
    }
  }
}

// ---------------- histogram of dst + packed (rank<<18)|dst --------------------
__global__ __launch_bounds__(TPB) void k_hist(const int* __restrict__ ei,
                                              int* __restrict__ cnt,
                                              unsigned* __restrict__ pd) {
  for (int e = blockIdx.x * TPB + threadIdx.x; e < EUI; e += gridDim.x * TPB) {
    const int dst = ei[EUI + e];
    const unsigned r = (unsigned)atomicAdd(&cnt[dst], 1);
    pd[e] = (r << 18) | (unsigned)dst;
  }
}

// ---------------- scan stage 1: per-block exclusive + block sums --------------
__global__ __launch_bounds__(TPB) void k_scan1(int* __restrict__ cnt,
                                               int* __restrict__ bsum) {
  __shared__ int sh[TPB];
  const int t = threadIdx.x;
  const int i = blockIdx.x * TPB + t;
  const int v = (i < NN) ? cnt[i] : 0;
  sh[t] = v;
  __syncthreads();
#pragma unroll
  for (int off = 1; off < TPB; off <<= 1) {
    int add = (t >= off) ? sh[t - off] : 0;
    __syncthreads();
    sh[t] += add;
    __syncthreads();
  }
  if (i < NN) cnt[i] = sh[t] - v;
  if (t == TPB - 1) bsum[blockIdx.x] = sh[t];
}

// ---------------- scan stages 2+3 merged --------------------------------------
__global__ __launch_bounds__(1024) void k_scan23(const int* __restrict__ excl,
                                                 const int* __restrict__ bsum,
                                                 int* __restrict__ rowptr) {
  __shared__ int sh[1024];
  const int t = threadIdx.x;
  const int v = (t < NSB) ? bsum[t] : 0;
  sh[t] = v;
  __syncthreads();
#pragma unroll
  for (int off = 1; off < 1024; off <<= 1) {
    int add = (t >= off) ? sh[t - off] : 0;
    __syncthreads();
    sh[t] += add;
    __syncthreads();
  }
  const int boff = sh[t] - v;
  __syncthreads();
  sh[t] = boff;
  __syncthreads();
  const int i = blockIdx.x * 1024 + t;
  if (i < NN) rowptr[i] = excl[i] + sh[i >> 8];
  if (i == 0) rowptr[NN] = EUI;
}

// ---------------- CSR fill (no atomics: p = rowptr[dst] + rank) ---------------
__global__ __launch_bounds__(TPB) void k_fill(const int* __restrict__ ei,
                                              const unsigned* __restrict__ pd,
                                              const int* __restrict__ rowptr,
                                              int* __restrict__ ssrc) {
  for (int e = blockIdx.x * TPB + threadIdx.x; e < EUI; e += gridDim.x * TPB) {
    const unsigned p = pd[e];
    ssrc[rowptr[p & 0x3ffffu] + (int)(p >> 18)] = ei[e];
  }
}

// ---------------- fused logits+exp+aggregate (bf16, DPP reduce) ---------------
// 16 lanes per node (= one DPP row), 4 nodes per wave, 2 edges per group per
// iteration. The 16-lane dot reduction is 4 v_add_f32+DPP (VALU pipe) -- no
// ds ops in the hot loop, and the per-group accumulator needs NO cross-slot
// epilogue. Unnormalized: out[n] = sum_e exp(leaky(dot)) * xW[src];
// psum[block] = partial sum of exp (softmax shift-invariant, |logit| < ~1).
__global__ __launch_bounds__(TPB) void k_fused(const int* __restrict__ rowptr,
                                               const int* __restrict__ ssrc,
                                               const unsigned* __restrict__ xwb,
                                               float* __restrict__ out,
                                               float* __restrict__ psum) {
  const int lane = threadIdx.x & 63;
  const int wv = threadIdx.x >> 6;
  const int sub = lane >> 4;   // node slot 0..3 (DPP row)
  const int q = lane & 15;     // dim quad 0..15
  const int n = blockIdx.x * 16 + wv * 4 + sub;  // < NN (NN == 16*NBF2)
  const uint2* __restrict__ x2 = (const uint2*)xwb;  // row stride 16 uint2
  const uint2 dv = x2[(size_t)n * 16 + q];
  const float vd0 = __uint_as_float(dv.x << 16);
  const float vd1 = __uint_as_float(dv.x & 0xffff0000u);
  const float vd2 = __uint_as_float(dv.y << 16);
  const float vd3 = __uint_as_float(dv.y & 0xffff0000u);
  const int b = rowptr[n], en = rowptr[n + 1];
  float a0 = 0.f, a1 = 0.f, a2 = 0.f, a3 = 0.f, wacc = 0.f;
  for (int it = b;; it += 2) {
    const bool act0 = it < en;
    if (!__any(act0)) break;
    const bool act1 = it + 1 < en;
    const int s0 = ssrc[act0 ? it : b];
    const int s1 = ssrc[act1 ? it + 1 : b];
    const uint2 sv0 = x2[(size_t)s0 * 16 + q];
    const uint2 sv1 = x2[(size_t)s1 * 16 + q];
    const float u0 = __uint_as_float(sv0.x << 16);
    const float u1 = __uint_as_float(sv0.x & 0xffff0000u);
    const float u2 = __uint_as_float(sv0.y << 16);
    const float u3 = __uint_as_float(sv0.y & 0xffff0000u);
    const float t0 = __uint_as_float(sv1.x << 16);
    const float t1 = __uint_as_float(sv1.x & 0xffff0000u);
    const float t2 = __uint_as_float(sv1.y << 16);
    const float t3 = __uint_as_float(sv1.y & 0xffff0000u);
    float p0 = vd0 * u0;
    p0 = fmaf(vd1, u1, p0);
    p0 = fmaf(vd2, u2, p0);
    p0 = fmaf(vd3, u3, p0);
    float p1 = vd0 * t0;
    p1 = fmaf(vd1, t1, p1);
    p1 = fmaf(vd2, t2, p1);
    p1 = fmaf(vd3, t3, p1);
    p0 = row16_sum(p0);
    p1 = row16_sum(p1);
    const float l0 = (p0 > 0.f) ? p0 : 0.2f * p0;
    const float l1 = (p1 > 0.f) ? p1 : 0.2f * p1;
    float w0 = __expf(l0);
    float w1 = __expf(l1);
    if (!act0) w0 = 0.f;
    if (!act1) w1 = 0.f;
    a0 = fmaf(w0, u0, a0);
    a1 = fmaf(w0, u1, a1);
    a2 = fmaf(w0, u2, a2);
    a3 = fmaf(w0, u3, a3);
    a0 = fmaf(w1, t0, a0);
    a1 = fmaf(w1, t1, a1);
    a2 = fmaf(w1, t2, a2);
    a3 = fmaf(w1, t3, a3);
    wacc += w0 + w1;   // group-uniform (same w on all 16 lanes)
  }
  float4 r = {a0, a1, a2, a3};
  ((float4*)(out + (size_t)n * DD))[q] = r;   // full row, no epilogue combine
  // block partial of sum(exp): one lane per group (q==0) holds wacc
  __shared__ float sm[16];
  if (q == 0) sm[wv * 4 + sub] = wacc;
  __syncthreads();
  if (threadIdx.x == 0) {
    float s = 0.f;
#pragma unroll
    for (int i = 0; i < 16; ++i) s += sm[i];
    psum[blockIdx.x] = s;
  }
}

// ---------------- total exp-sum -----------------------------------------------
__global__ __launch_bounds__(TPB) void k_rsum(const float* __restrict__ psum,
                                              float* __restrict__ scal) {
  float s = 0.f;
  for (int i = threadIdx.x; i < NBF2; i += TPB) s += psum[i];
#pragma unroll
  for (int off = 32; off; off >>= 1) s += __shfl_xor(s, off, 64);
  __shared__ float sm[4];
  if ((threadIdx.x & 63) == 0) sm[threadIdx.x >> 6] = s;
  __syncthreads();
  if (threadIdx.x == 0) scal[0] = sm[0] + sm[1] + sm[2] + sm[3];
}

// ---------------- out = relu(out / sumexp) ------------------------------------
__global__ __launch_bounds__(TPB) void k_scale(float* __restrict__ out,
                                               const float* __restrict__ scal) {
  const float inv = 1.0f / scal[0];
  const int i = blockIdx.x * TPB + threadIdx.x;
  float4* o4 = (float4*)out;
  float4 v = o4[i];
  v.x = fmaxf(v.x * inv, 0.f);
  v.y = fmaxf(v.y * inv, 0.f);
  v.z = fmaxf(v.z * inv, 0.f);
  v.w = fmaxf(v.w * inv, 0.f);
  o4[i] = v;
}

extern "C" void kernel_launch(void* const* d_in, const int* in_sizes, int n_in,
                              void* d_out, int out_size, void* d_ws, size_t ws_size,
                              hipStream_t stream) {
  const int* uidx = (const int*)d_in[0];
  const int* iidx = (const int*)d_in[1];
  const int* ei_ui = (const int*)d_in[2];
  // d_in[3], d_in[4], d_in[8] (KG graph, W_r): dead code in the reference
  // (x_kg is added into x, then x is fully overwritten by relu(x_ui)).
  const float* ut = (const float*)d_in[5];
  const float* et = (const float*)d_in[6];
  const float* W = (const float*)d_in[7];

  float* out = (float*)d_out;
  float* ws = (float*)d_ws;
  unsigned* xwb = (unsigned*)(ws + XWB_OFF);
  unsigned* pd = (unsigned*)(ws + PD_OFF);
  int* ssrc = (int*)(ws + SSRC_OFF);
  int* cnt = (int*)(ws + CNT_OFF);
  int* rowptr = (int*)(ws + ROWPTR_OFF);
  int* bsum = (int*)(ws + BSUM_OFF);
  float* psum = ws + PSUM_OFF;
  float* scal = ws + SCAL_OFF;

  (void)hipMemsetAsync(cnt, 0, (size_t)NN * sizeof(int), stream);

  k_xw<<<NXB, TPB, 0, stream>>>(uidx, iidx, ut, et, W, xwb);
  k_hist<<<NBLK, TPB, 0, stream>>>(ei_ui, cnt, pd);
  k_scan1<<<NSB, TPB, 0, stream>>>(cnt, bsum);
  k_scan23<<<NS23, 1024, 0, stream>>>(cnt, bsum, rowptr);
  k_fill<<<NBLK, TPB, 0, stream>>>(ei_ui, pd, rowptr, ssrc);
  k_fused<<<NBF2, TPB, 0, stream>>>(rowptr, ssrc, xwb, out, psum);
  k_rsum<<<1, TPB, 0, stream>>>(psum, scal);
  k_scale<<<NSC, TPB, 0, stream>>>(out, scal);
}